// Round 11
// baseline (64.706 us; speedup 1.0000x reference)
//
#include <hip/hip_runtime.h>

#define BATCH 4
#define SEQ   4096
#define CDIM  1024
#define HDIM  64

typedef __attribute__((ext_vector_type(8))) short bf16x8;
typedef __attribute__((ext_vector_type(4))) float f32x4;

// ws layout (in shorts):
//   wt2   [32 k0g][12 p][64 slot][8]            (bf16, frag order; slot = lr*4+lg) @ 0
//   q     [16384][64]   (bf16, row-major)       @ Q_OFF
//   kfrag [4][64 kb64][4 st][2 half][512]       @ KF_OFF
//   vfrag [4][64 kb64][2 half][4 hc][512]       @ VF_OFF
//   xbf   [16384][1024] (bf16, row-major)       @ XBF_OFF
#define WT_OFF  0
#define Q_OFF   (3 * HDIM * CDIM)
#define KF_OFF  (Q_OFF + BATCH * SEQ * HDIM)
#define VF_OFF  (KF_OFF + BATCH * SEQ * HDIM)
#define XBF_OFF (VF_OFF + BATCH * SEQ * HDIM)

static __device__ __forceinline__ short f2bf(float f) {
  union { float f; unsigned u; } a; a.f = f;
  unsigned r = a.u + 0x7fffu + ((a.u >> 16) & 1u);   // RNE
  return (short)(r >> 16);
}

static __device__ __forceinline__ unsigned cvtpk(float lo, float hi) {
  unsigned r;
  asm("v_cvt_pk_bf16_f32 %0, %1, %2" : "=v"(r) : "v"(lo), "v"(hi));
  return r;
}

static __device__ __forceinline__ bf16x8 ld8(const short* p) {
  return *(const bf16x8*)p;
}

static __device__ __forceinline__ void gld_lds16(const short* g, short* l) {
  __builtin_amdgcn_global_load_lds(
      (const __attribute__((address_space(1))) void*)g,
      (__attribute__((address_space(3))) void*)l, 16, 0, 0);
}

// ------------- kernel 0: x -> bf16 (row-major) + W -> bf16 frag order -------
__global__ void cvt_kernel(const float* __restrict__ x,
                           const float* __restrict__ wq, const float* __restrict__ wk,
                           const float* __restrict__ wv, short* __restrict__ ws) {
  int gb = blockIdx.x;
  if (gb < 8192) {
    // x: thread handles 8 consecutive fp32 -> bf16x8
    int idx = gb * 256 + threadIdx.x;
    const float* src = x + (size_t)idx * 8;
    float4 f1 = *(const float4*)src;
    float4 f2 = *(const float4*)(src + 4);
    union { unsigned u[4]; bf16x8 v; } o;
    o.u[0] = cvtpk(f1.x, f1.y);
    o.u[1] = cvtpk(f1.z, f1.w);
    o.u[2] = cvtpk(f2.x, f2.y);
    o.u[3] = cvtpk(f2.z, f2.w);
    *(bf16x8*)(ws + XBF_OFF + (size_t)idx * 8) = o.v;
  } else {
    // W -> wt2 fragment order (unchanged mapping)
    int idx = (gb - 8192) * 256 + threadIdx.x;   // 0 .. 3*65536-1
    int m = idx >> 16;
    int f = idx & 65535;
    int k0g = f >> 11, hc = (f >> 9) & 3, lr = (f >> 5) & 15, lg = (f >> 3) & 3, j = f & 7;
    int c = k0g * 32 + lg * 8 + j, h = hc * 16 + lr;
    const float* w = (m == 0) ? wq : (m == 1) ? wk : wv;
    ws[WT_OFF + ((k0g * 12 + m * 4 + hc) * 64 + lr * 4 + lg) * 8 + j] = f2bf(w[c * 64 + h]);
  }
}

// ---------------- kernel 1: fused q/k/v projection ----------------
// block = 32 rows, 12 waves; wave w owns product p=w for BOTH row-tiles.
// x staged bf16 via async global_load_lds (pre-swizzled source), dbuf, 4 phases.
__global__ __launch_bounds__(768, 6) void proj_kernel(const short* __restrict__ xbf,
                                                      const short* __restrict__ wt2,
                                                      short* __restrict__ ws) {
  __shared__ short xlds[2][32 * 256];    // 2 x 16KB; row = 512B, XOR-swizzled content
  __shared__ short k_lds[4][2][16][16];  // [hc][rt][t16][h16]
  __shared__ short v_lds[4][2][16][16];  // [hc][rt][h16][t16]

  int tid = threadIdx.x;
  int widx = tid >> 6, lane = tid & 63;
  int lr = lane & 15, lg = lane >> 4;
  int row0 = blockIdx.x * 32;
  int p = widx;              // product id 0..11
  int m = p >> 2, hcw = p & 3;

  // staging (waves 0-7): 2 glds each, covering rows widx*4 .. widx*4+3
  int srow2a = widx * 4;          // rows srow2a, srow2a+1   (instr i=0)
  int slrow0 = srow2a + (lane >> 5);
  int slrow1 = srow2a + 2 + (lane >> 5);
  int sck = (lane & 31) * 16;
  // per-lane pre-swizzled source byte offsets within the 512B row segment
  int soff0 = sck ^ ((slrow0 & 7) << 4);
  int soff1 = sck ^ ((slrow1 & 7) << 4);
  const short* xsrc0 = xbf + (size_t)(row0 + slrow0) * 1024 + (soff0 >> 1);
  const short* xsrc1 = xbf + (size_t)(row0 + slrow1) * 1024 + (soff1 >> 1);

#define STAGE(BUF, PH) do {                                                  \
    if (widx < 8) {                                                          \
      gld_lds16(xsrc0 + (PH) * 256, &xlds[(BUF)][srow2a * 256]);             \
      gld_lds16(xsrc1 + (PH) * 256, &xlds[(BUF)][(srow2a + 2) * 256]);       \
    }                                                                        \
  } while (0)

  // A-read addressing (swizzled): row rt*16+lr, row&7 == lr&7
  int abase0 = lr * 512, abase1 = (16 + lr) * 512;
  int axor = (lr & 7) << 4;

  // B pointer: this wave's product; wt2 slot order is lr*4+lg
  const short* bptr = wt2 + p * 512 + (lr * 4 + lg) * 8;

  f32x4 acc[2] = {};   // [rt]

#define PCOMPUTE(BUF, PH) do {                                               \
    const char* bufc_ = (const char*)&xlds[(BUF)][0];                        \
    _Pragma("unroll")                                                        \
    for (int kk = 0; kk < 8; ++kk) {                                         \
      int co_ = (kk * 64 + lg * 16) ^ axor;                                  \
      bf16x8 af0_ = *(const bf16x8*)(bufc_ + abase0 + co_);                  \
      bf16x8 af1_ = *(const bf16x8*)(bufc_ + abase1 + co_);                  \
      bf16x8 bf_  = ld8(bptr + ((PH) * 8 + kk) * 6144);                      \
      acc[0] = __builtin_amdgcn_mfma_f32_16x16x32_bf16(af0_, bf_, acc[0], 0, 0, 0); \
      acc[1] = __builtin_amdgcn_mfma_f32_16x16x32_bf16(af1_, bf_, acc[1], 0, 0, 0); \
    }                                                                        \
  } while (0)

  STAGE(0, 0);
  __syncthreads();
#pragma unroll
  for (int ph = 0; ph < 4; ++ph) {
    if (ph < 3) STAGE((ph + 1) & 1, ph + 1);   // async prefetch next phase
    PCOMPUTE(ph & 1, ph);
    __syncthreads();                            // drains vmcnt (stage) + lgkm
  }

  // ---- stores (R6-verified fragment mapping, per row-tile) ----
  short* qs  = ws + Q_OFF;
  short* kfr = ws + KF_OFF;
  short* vfr = ws + VF_OFF;

  if (m == 0) {
#pragma unroll
    for (int rt = 0; rt < 2; ++rt) {
      int rbase = row0 + rt * 16;
#pragma unroll
      for (int reg = 0; reg < 4; ++reg)
        qs[(rbase + lg * 4 + reg) * 64 + hcw * 16 + lr] = f2bf(acc[rt][reg]);
    }
  } else if (m == 1) {
#pragma unroll
    for (int rt = 0; rt < 2; ++rt)
#pragma unroll
      for (int reg = 0; reg < 4; ++reg)
        k_lds[hcw][rt][lg * 4 + reg][lr] = f2bf(acc[rt][reg]);   // [t16][h16]
    if (lane < 32) {
      int i0 = lane >> 1, f8 = (lane & 1) * 8;
#pragma unroll
      for (int rt = 0; rt < 2; ++rt) {
        int rbase = row0 + rt * 16;
        int b = rbase >> 12, tb = rbase & (SEQ - 1);
        int kb64 = tb >> 6, st = (tb >> 4) & 3;
        size_t kblk = ((((size_t)b * 64 + kb64) * 4 + st) * 2 + (hcw >> 1)) * 512;
        bf16x8 kv8 = *(const bf16x8*)(&k_lds[hcw][rt][i0][f8]);
        *(bf16x8*)(kfr + kblk + ((hcw & 1) * 2 + (f8 >> 3)) * 128 + i0 * 8) = kv8;
      }
    }
  } else {
#pragma unroll
    for (int rt = 0; rt < 2; ++rt)
#pragma unroll
      for (int reg = 0; reg < 4; ++reg)
        v_lds[hcw][rt][lr][lg * 4 + reg] = f2bf(acc[rt][reg]);   // [h16][t16]
    if (lane < 32) {
      int i0 = lane >> 1, f8 = (lane & 1) * 8;
#pragma unroll
      for (int rt = 0; rt < 2; ++rt) {
        int rbase = row0 + rt * 16;
        int b = rbase >> 12, tb = rbase & (SEQ - 1);
        int kb64 = tb >> 6;
        size_t vblk = ((((size_t)b * 64 + kb64) * 2 + ((tb >> 5) & 1)) * 4 + hcw) * 512;
        bf16x8 vv8 = *(const bf16x8*)(&v_lds[hcw][rt][i0][f8]);
        *(bf16x8*)(vfr + vblk + (((tb & 16) + f8) >> 3) * 128 + i0 * 8) = vv8;
      }
    }
  }
}

// ---------------- kernel 2: causal flash attention (no-max softmax) ----------
// 512 blocks x 512 thr; block g processes 16-row tiles g and 1023-g
// (heavy-first ordering -> per-block work constant). 8 waves split KV 8-way.
__global__ __launch_bounds__(512, 4) void attn_kernel(const short* __restrict__ ws,
                                                      float* __restrict__ out) {
  __shared__ float p_o[8][4][4][64];    // 32KB
  __shared__ float p_l[8][4][64];       // 8KB
  __shared__ short plds[8][16][72];     // 18KB

  int widx = threadIdx.x >> 6, lane = threadIdx.x & 63;
  int lr = lane & 15, lg = lane >> 4;
  int g = blockIdx.x;

  const short* qs  = ws + Q_OFF;
  const short* kfr = ws + KF_OFF;
  const short* vfr = ws + VF_OFF;
  short* myp = &plds[widx][0][0];

  for (int tt = 0; tt < 2; ++tt) {
    int j = tt == 0 ? g : 1023 - g;
    int t16 = 255 - (j >> 2), b = j & 3;     // heavy-first tile ordering
    int qrow0 = b * SEQ + t16 * 16;
    int nkv = (t16 >> 2) + 1;                // # of 64-wide kv blocks

    bf16x8 qf0 = ld8(qs + (qrow0 + lr) * 64 + lg * 8);
    bf16x8 qf1 = ld8(qs + (qrow0 + lr) * 64 + 32 + lg * 8);
    const short* kb_b = kfr + (size_t)b * 64 * 4096 + lane * 8;
    const short* vb_b = vfr + (size_t)b * 64 * 4096 + lane * 8;

    f32x4 o[4] = {};
    float l_run[4] = {};

    if (tt) __syncthreads();   // guard LDS reuse across tiles

    bf16x8 kf[8];
    int kvb = widx;
    if (kvb < nkv) {
      const short* kb = kb_b + (size_t)kvb * 4096;
#pragma unroll
      for (int q8 = 0; q8 < 8; ++q8) kf[q8] = ld8(kb + q8 * 512);
    }

    for (; kvb < nkv; kvb += 8) {
      int kv0 = kvb * 64;

      f32x4 s[4] = {};
#pragma unroll
      for (int st = 0; st < 4; ++st) {
        s[st] = __builtin_amdgcn_mfma_f32_16x16x32_bf16(qf0, kf[st * 2],     s[st], 0, 0, 0);
        s[st] = __builtin_amdgcn_mfma_f32_16x16x32_bf16(qf1, kf[st * 2 + 1], s[st], 0, 0, 0);
      }

      // V fragments: coalesced 1KB loads; latency hides under exp+LDS roundtrip
      bf16x8 vv[8];
      {
        const short* vb = vb_b + (size_t)kvb * 4096;
#pragma unroll
        for (int q8 = 0; q8 < 8; ++q8) vv[q8] = ld8(vb + q8 * 512);
      }
      // prefetch next K block
      int kvn = kvb + 8;
      if (kvn < nkv) {
        const short* kb = kb_b + (size_t)kvn * 4096;
#pragma unroll
        for (int q8 = 0; q8 < 8; ++q8) kf[q8] = ld8(kb + q8 * 512);
      }

      bool last = (kvb == nkv - 1);
#pragma unroll
      for (int reg = 0; reg < 4; ++reg) {
        int ig = t16 * 16 + lg * 4 + reg;
#pragma unroll
        for (int st = 0; st < 4; ++st) {
          float v = s[st][reg] * 0.125f;
          if (last && (kv0 + st * 16 + lr > ig)) v = -1e30f;
          float p = __expf(v);
          l_run[reg] += p;
          myp[(lg * 4 + reg) * 72 + st * 16 + lr] = f2bf(p);
        }
      }
      asm volatile("s_waitcnt lgkmcnt(0)" ::: "memory");
      bf16x8 pf0 = ld8(myp + lr * 72 + lg * 8);
      bf16x8 pf1 = ld8(myp + lr * 72 + 32 + lg * 8);

#pragma unroll
      for (int hc = 0; hc < 4; ++hc) {
        o[hc] = __builtin_amdgcn_mfma_f32_16x16x32_bf16(pf0, vv[hc],     o[hc], 0, 0, 0);
        o[hc] = __builtin_amdgcn_mfma_f32_16x16x32_bf16(pf1, vv[4 + hc], o[hc], 0, 0, 0);
      }
    }

    // in-lane l -> row sum
#pragma unroll
    for (int reg = 0; reg < 4; ++reg) {
      float l = l_run[reg];
      l += __shfl_xor(l, 1);
      l += __shfl_xor(l, 2);
      l += __shfl_xor(l, 4);
      l += __shfl_xor(l, 8);
      l_run[reg] = l;
    }

    // publish partials
#pragma unroll
    for (int hc = 0; hc < 4; ++hc)
#pragma unroll
      for (int reg = 0; reg < 4; ++reg)
        p_o[widx][hc][reg][lane] = o[hc][reg];
#pragma unroll
    for (int reg = 0; reg < 4; ++reg)
      p_l[widx][reg][lane] = l_run[reg];
    __syncthreads();

    // merge: waves 0-3 handle reg = widx; plain sums (no-max softmax)
    if (widx < 4) {
      int reg = widx;
      float lsum = 0.f;
#pragma unroll
      for (int w = 0; w < 8; ++w) lsum += p_l[w][reg][lane];
      float inv = 1.0f / lsum;
#pragma unroll
      for (int hc = 0; hc < 4; ++hc) {
        float sv = 0.f;
#pragma unroll
        for (int w = 0; w < 8; ++w) sv += p_o[w][hc][reg][lane];
        out[(qrow0 + lg * 4 + reg) * 64 + hc * 16 + lr] = sv * inv;
      }
    }
  }
}

extern "C" void kernel_launch(void* const* d_in, const int* in_sizes, int n_in,
                              void* d_out, int out_size, void* d_ws, size_t ws_size,
                              hipStream_t stream) {
  const float* x  = (const float*)d_in[0];
  const float* wq = (const float*)d_in[1];
  const float* wk = (const float*)d_in[2];
  const float* wv = (const float*)d_in[3];
  short* ws = (short*)d_ws;
  float* out = (float*)d_out;

  cvt_kernel<<<dim3(8960), dim3(256), 0, stream>>>(x, wq, wk, wv, ws);
  proj_kernel<<<dim3(512), dim3(768), 0, stream>>>(ws + XBF_OFF, ws + WT_OFF, ws);
  attn_kernel<<<dim3(512), dim3(512), 0, stream>>>(ws, out);
}

// Round 12
// 62.914 us; speedup vs baseline: 1.0285x; 1.0285x over previous
//
#include <hip/hip_runtime.h>

#define BATCH 4
#define SEQ   4096
#define CDIM  1024
#define HDIM  64

typedef __attribute__((ext_vector_type(8))) short bf16x8;
typedef __attribute__((ext_vector_type(4))) float f32x4;

// ws layout (in shorts):
//   wt2   [32 k0g][12 p][64 slot][8]            (bf16, frag order; slot = lr*4+lg) @ 0
//   q     [16384][64]   (bf16, row-major)       @ Q_OFF
//   kfrag [4][64 kb64][4 st][2 half][512]       @ KF_OFF
//   vfrag [4][64 kb64][2 half][4 hc][512]       @ VF_OFF
//   k/v fragment interior: [lg][lr][j] = lg*128 + lr*8 + j  (lane*8+j)
#define WT_OFF  0
#define Q_OFF   (3 * HDIM * CDIM)
#define KF_OFF  (Q_OFF + BATCH * SEQ * HDIM)
#define VF_OFF  (KF_OFF + BATCH * SEQ * HDIM)

static __device__ __forceinline__ short f2bf(float f) {
  union { float f; unsigned u; } a; a.f = f;
  unsigned r = a.u + 0x7fffu + ((a.u >> 16) & 1u);   // RNE
  return (short)(r >> 16);
}

static __device__ __forceinline__ unsigned cvtpk(float lo, float hi) {
  unsigned r;
  asm("v_cvt_pk_bf16_f32 %0, %1, %2" : "=v"(r) : "v"(lo), "v"(hi));
  return r;
}

static __device__ __forceinline__ bf16x8 ld8(const short* p) {
  return *(const bf16x8*)p;
}

// ---------------- kernel 0: W -> bf16, MFMA-fragment order ----------------
__global__ void wcvt_kernel(const float* __restrict__ wq, const float* __restrict__ wk,
                            const float* __restrict__ wv, short* __restrict__ wt2) {
  int idx = blockIdx.x * 256 + threadIdx.x;   // 0 .. 3*65536-1
  int m = idx >> 16;
  int f = idx & 65535;
  int k0g = f >> 11, hc = (f >> 9) & 3, lr = (f >> 5) & 15, lg = (f >> 3) & 3, j = f & 7;
  int c = k0g * 32 + lg * 8 + j, h = hc * 16 + lr;
  const float* w = (m == 0) ? wq : (m == 1) ? wk : wv;
  wt2[((k0g * 12 + m * 4 + hc) * 64 + lr * 4 + lg) * 8 + j] = f2bf(w[c * 64 + h]);
}

// ---------------- kernel 1: fused q/k/v projection ----------------
// block = 32 rows, 4 waves (256 thr); persistent 64KB LDS x-cache (bf16,
// XOR-swizzled), filled once (fp32->bf16 in regs), ONE barrier, then a
// barrier-free compute loop: wave w owns hc=w for all 3 m's, both row-tiles:
// per kk = 2 ds_read_b128 + 3 B-loads + 6 MFMA.
__global__ __launch_bounds__(256, 2) void proj_kernel(const float* __restrict__ x,
                                                      const short* __restrict__ wt2,
                                                      short* __restrict__ ws) {
  __shared__ short xc[32 * 1024];        // 64KB x-cache; row = 2KB, 16B-slot swizzle
  __shared__ short k_lds[4][2][16][16];  // [hc][rt][t16][h16]
  __shared__ short v_lds[4][2][16][16];  // [hc][rt][h16][t16]

  int tid = threadIdx.x;
  int w = tid >> 6, lane = tid & 63;
  int lr = lane & 15, lg = lane >> 4;
  int row0 = blockIdx.x * 32;

  // ---- stage: fp32 x -> bf16 LDS cache, swizzled, coalesced ----
  {
    int r = tid >> 3, t8 = tid & 7;
    const float* xrow = x + (size_t)(row0 + r) * CDIM;
    char* xcb = (char*)xc + r * 2048;
    int rx = (r & 7) << 4;
#pragma unroll
    for (int j = 0; j < 16; ++j) {
      int c0 = t8 * 8 + j * 64;          // fp32 col of this 8-float chunk
      float4 f1 = *(const float4*)(xrow + c0);
      float4 f2 = *(const float4*)(xrow + c0 + 4);
      union { unsigned u[4]; bf16x8 v; } o;
      o.u[0] = cvtpk(f1.x, f1.y); o.u[1] = cvtpk(f1.z, f1.w);
      o.u[2] = cvtpk(f2.x, f2.y); o.u[3] = cvtpk(f2.z, f2.w);
      int slot = t8 + j * 8;             // 16B slot within row (0..127)
      *(bf16x8*)(xcb + ((slot * 16) ^ rx)) = o.v;
    }
  }
  __syncthreads();

  // ---- compute: barrier-free ----
  const char* xcb = (const char*)xc;
  int axor = (lr & 7) << 4;
  const short* bptr = wt2 + w * 512 + (lr * 4 + lg) * 8;

  f32x4 acc[3][2] = {};   // [m][rt]
#pragma unroll 8
  for (int kk = 0; kk < 32; ++kk) {
    int co = (kk * 64 + lg * 16) ^ axor;
    bf16x8 a0 = *(const bf16x8*)(xcb + lr * 2048 + co);
    bf16x8 a1 = *(const bf16x8*)(xcb + (16 + lr) * 2048 + co);
    const short* bk = bptr + kk * 6144;
#pragma unroll
    for (int m = 0; m < 3; ++m) {
      bf16x8 bf = ld8(bk + m * 2048);    // p = m*4 + w -> p*512 = m*2048 + w*512
      acc[m][0] = __builtin_amdgcn_mfma_f32_16x16x32_bf16(a0, bf, acc[m][0], 0, 0, 0);
      acc[m][1] = __builtin_amdgcn_mfma_f32_16x16x32_bf16(a1, bf, acc[m][1], 0, 0, 0);
    }
  }

  // ---- stores (R10-verified fragment mapping; hcw = w) ----
  short* qs  = ws + Q_OFF;
  short* kfr = ws + KF_OFF;
  short* vfr = ws + VF_OFF;
  int hcw = w;

#pragma unroll
  for (int rt = 0; rt < 2; ++rt) {
    int rbase = row0 + rt * 16;
#pragma unroll
    for (int reg = 0; reg < 4; ++reg) {
      qs[(rbase + lg * 4 + reg) * 64 + hcw * 16 + lr] = f2bf(acc[0][rt][reg]);
      k_lds[hcw][rt][lg * 4 + reg][lr] = f2bf(acc[1][rt][reg]);   // [t16][h16]
      v_lds[hcw][rt][lr][lg * 4 + reg] = f2bf(acc[2][rt][reg]);   // [h16][t16]
    }
  }
  if (lane < 32) {
    int i0 = lane >> 1, f8 = (lane & 1) * 8;
#pragma unroll
    for (int rt = 0; rt < 2; ++rt) {
      int rbase = row0 + rt * 16;
      int b = rbase >> 12, tb = rbase & (SEQ - 1);
      int kb64 = tb >> 6, st = (tb >> 4) & 3;
      size_t kblk = ((((size_t)b * 64 + kb64) * 4 + st) * 2 + (hcw >> 1)) * 512;
      bf16x8 kv8 = *(const bf16x8*)(&k_lds[hcw][rt][i0][f8]);
      *(bf16x8*)(kfr + kblk + ((hcw & 1) * 2 + (f8 >> 3)) * 128 + i0 * 8) = kv8;
      size_t vblk = ((((size_t)b * 64 + kb64) * 2 + ((tb >> 5) & 1)) * 4 + hcw) * 512;
      bf16x8 vv8 = *(const bf16x8*)(&v_lds[hcw][rt][i0][f8]);
      *(bf16x8*)(vfr + vblk + (((tb & 16) + f8) >> 3) * 128 + i0 * 8) = vv8;
    }
  }
}

// ---------------- kernel 2: causal flash attention (no-max softmax) ----------
// 512 blocks x 512 thr; block g processes 16-row tiles g and 1023-g
// (heavy-first ordering -> per-block work constant). 8 waves split KV 8-way.
__global__ __launch_bounds__(512, 4) void attn_kernel(const short* __restrict__ ws,
                                                      float* __restrict__ out) {
  __shared__ float p_o[8][4][4][64];    // 32KB
  __shared__ float p_l[8][4][64];       // 8KB
  __shared__ short plds[8][16][72];     // 18KB

  int widx = threadIdx.x >> 6, lane = threadIdx.x & 63;
  int lr = lane & 15, lg = lane >> 4;
  int g = blockIdx.x;

  const short* qs  = ws + Q_OFF;
  const short* kfr = ws + KF_OFF;
  const short* vfr = ws + VF_OFF;
  short* myp = &plds[widx][0][0];

  for (int tt = 0; tt < 2; ++tt) {
    int j = tt == 0 ? g : 1023 - g;
    int t16 = 255 - (j >> 2), b = j & 3;     // heavy-first tile ordering
    int qrow0 = b * SEQ + t16 * 16;
    int nkv = (t16 >> 2) + 1;                // # of 64-wide kv blocks

    bf16x8 qf0 = ld8(qs + (qrow0 + lr) * 64 + lg * 8);
    bf16x8 qf1 = ld8(qs + (qrow0 + lr) * 64 + 32 + lg * 8);
    const short* kb_b = kfr + (size_t)b * 64 * 4096 + lane * 8;
    const short* vb_b = vfr + (size_t)b * 64 * 4096 + lane * 8;

    f32x4 o[4] = {};
    float l_run[4] = {};

    if (tt) __syncthreads();   // guard LDS reuse across tiles

    bf16x8 kf[8];
    int kvb = widx;
    if (kvb < nkv) {
      const short* kb = kb_b + (size_t)kvb * 4096;
#pragma unroll
      for (int q8 = 0; q8 < 8; ++q8) kf[q8] = ld8(kb + q8 * 512);
    }

    for (; kvb < nkv; kvb += 8) {
      int kv0 = kvb * 64;

      f32x4 s[4] = {};
#pragma unroll
      for (int st = 0; st < 4; ++st) {
        s[st] = __builtin_amdgcn_mfma_f32_16x16x32_bf16(qf0, kf[st * 2],     s[st], 0, 0, 0);
        s[st] = __builtin_amdgcn_mfma_f32_16x16x32_bf16(qf1, kf[st * 2 + 1], s[st], 0, 0, 0);
      }

      // V fragments: coalesced 1KB loads; latency hides under exp+LDS roundtrip
      bf16x8 vv[8];
      {
        const short* vb = vb_b + (size_t)kvb * 4096;
#pragma unroll
        for (int q8 = 0; q8 < 8; ++q8) vv[q8] = ld8(vb + q8 * 512);
      }
      // prefetch next K block
      int kvn = kvb + 8;
      if (kvn < nkv) {
        const short* kb = kb_b + (size_t)kvn * 4096;
#pragma unroll
        for (int q8 = 0; q8 < 8; ++q8) kf[q8] = ld8(kb + q8 * 512);
      }

      bool last = (kvb == nkv - 1);
#pragma unroll
      for (int reg = 0; reg < 4; ++reg) {
        int ig = t16 * 16 + lg * 4 + reg;
#pragma unroll
        for (int st = 0; st < 4; ++st) {
          float v = s[st][reg] * 0.125f;
          if (last && (kv0 + st * 16 + lr > ig)) v = -1e30f;
          float p = __expf(v);
          l_run[reg] += p;
          myp[(lg * 4 + reg) * 72 + st * 16 + lr] = f2bf(p);
        }
      }
      asm volatile("s_waitcnt lgkmcnt(0)" ::: "memory");
      bf16x8 pf0 = ld8(myp + lr * 72 + lg * 8);
      bf16x8 pf1 = ld8(myp + lr * 72 + 32 + lg * 8);

#pragma unroll
      for (int hc = 0; hc < 4; ++hc) {
        o[hc] = __builtin_amdgcn_mfma_f32_16x16x32_bf16(pf0, vv[hc],     o[hc], 0, 0, 0);
        o[hc] = __builtin_amdgcn_mfma_f32_16x16x32_bf16(pf1, vv[4 + hc], o[hc], 0, 0, 0);
      }
    }

    // in-lane l -> row sum
#pragma unroll
    for (int reg = 0; reg < 4; ++reg) {
      float l = l_run[reg];
      l += __shfl_xor(l, 1);
      l += __shfl_xor(l, 2);
      l += __shfl_xor(l, 4);
      l += __shfl_xor(l, 8);
      l_run[reg] = l;
    }

    // publish partials
#pragma unroll
    for (int hc = 0; hc < 4; ++hc)
#pragma unroll
      for (int reg = 0; reg < 4; ++reg)
        p_o[widx][hc][reg][lane] = o[hc][reg];
#pragma unroll
    for (int reg = 0; reg < 4; ++reg)
      p_l[widx][reg][lane] = l_run[reg];
    __syncthreads();

    // merge: waves 0-3 handle reg = widx; plain sums (no-max softmax)
    if (widx < 4) {
      int reg = widx;
      float lsum = 0.f;
#pragma unroll
      for (int w2 = 0; w2 < 8; ++w2) lsum += p_l[w2][reg][lane];
      float inv = 1.0f / lsum;
#pragma unroll
      for (int hc = 0; hc < 4; ++hc) {
        float sv = 0.f;
#pragma unroll
        for (int w2 = 0; w2 < 8; ++w2) sv += p_o[w2][hc][reg][lane];
        out[(qrow0 + lg * 4 + reg) * 64 + hc * 16 + lr] = sv * inv;
      }
    }
  }
}

extern "C" void kernel_launch(void* const* d_in, const int* in_sizes, int n_in,
                              void* d_out, int out_size, void* d_ws, size_t ws_size,
                              hipStream_t stream) {
  const float* x  = (const float*)d_in[0];
  const float* wq = (const float*)d_in[1];
  const float* wk = (const float*)d_in[2];
  const float* wv = (const float*)d_in[3];
  short* ws = (short*)d_ws;
  float* out = (float*)d_out;

  wcvt_kernel<<<dim3(768), dim3(256), 0, stream>>>(wq, wk, wv, ws + WT_OFF);
  proj_kernel<<<dim3(512), dim3(256), 0, stream>>>(x, ws + WT_OFF, ws);
  attn_kernel<<<dim3(512), dim3(512), 0, stream>>>(ws, out);
}

// Round 13
// 57.062 us; speedup vs baseline: 1.1340x; 1.1026x over previous
//
#include <hip/hip_runtime.h>

#define BATCH 4
#define SEQ   4096
#define CDIM  1024
#define HDIM  64

typedef __attribute__((ext_vector_type(8))) short bf16x8;
typedef __attribute__((ext_vector_type(4))) float f32x4;

// ws layout (in shorts):
//   wt2   [32 k0g][12 p][64 slot][8]            (bf16, frag order; slot = lr*4+lg) @ 0
//   q     [16384][64]   (bf16, row-major)       @ Q_OFF
//   kfrag [4][64 kb64][4 st][2 half][512]       @ KF_OFF
//   vfrag [4][64 kb64][2 half][4 hc][512]       @ VF_OFF
//   k/v fragment interior: [lg][lr][j] = lg*128 + lr*8 + j  (lane*8+j)
#define WT_OFF  0
#define Q_OFF   (3 * HDIM * CDIM)
#define KF_OFF  (Q_OFF + BATCH * SEQ * HDIM)
#define VF_OFF  (KF_OFF + BATCH * SEQ * HDIM)

static __device__ __forceinline__ short f2bf(float f) {
  union { float f; unsigned u; } a; a.f = f;
  unsigned r = a.u + 0x7fffu + ((a.u >> 16) & 1u);   // RNE
  return (short)(r >> 16);
}

static __device__ __forceinline__ unsigned cvtpk(float lo, float hi) {
  unsigned r;
  asm("v_cvt_pk_bf16_f32 %0, %1, %2" : "=v"(r) : "v"(lo), "v"(hi));
  return r;
}

static __device__ __forceinline__ bf16x8 ld8(const short* p) {
  return *(const bf16x8*)p;
}

// ---------------- kernel 0: W -> bf16, MFMA-fragment order ----------------
__global__ void wcvt_kernel(const float* __restrict__ wq, const float* __restrict__ wk,
                            const float* __restrict__ wv, short* __restrict__ wt2) {
  int idx = blockIdx.x * 256 + threadIdx.x;   // 0 .. 3*65536-1
  int m = idx >> 16;
  int f = idx & 65535;
  int k0g = f >> 11, hc = (f >> 9) & 3, lr = (f >> 5) & 15, lg = (f >> 3) & 3, j = f & 7;
  int c = k0g * 32 + lg * 8 + j, h = hc * 16 + lr;
  const float* w = (m == 0) ? wq : (m == 1) ? wk : wv;
  wt2[((k0g * 12 + m * 4 + hc) * 64 + lr * 4 + lg) * 8 + j] = f2bf(w[c * 64 + h]);
}

// ---------------- kernel 1: fused q/k/v projection ----------------
// block = 64 rows (4 row-tiles), 12 waves; wave p owns product p for ALL 4
// row-tiles: per kk = 4 ds_read_b128 + 1 B-load + 4 MFMA (B reuse x4; half
// the wt2 fan-out of 512-block versions). x staged per K-phase (256) in a
// 32KB XOR-swizzled LDS tile, double-buffered, T14 issue-early/write-late.
__global__ __launch_bounds__(768, 3) void proj_kernel(const float* __restrict__ x,
                                                      const short* __restrict__ wt2,
                                                      short* __restrict__ ws) {
  __shared__ short xph[2][64 * 256];     // 2 x 32KB, swizzled
  __shared__ short k_lds[4][4][16][16];  // [hc][rt][t16][h16]  8KB
  __shared__ short v_lds[4][4][16][16];  // [hc][rt][h16][t16]  8KB

  int tid = threadIdx.x;
  int widx = tid >> 6, lane = tid & 63;
  int lr = lane & 15, lg = lane >> 4;
  int row0 = blockIdx.x * 64;
  int p = widx;              // product id 0..11
  int m = p >> 2, hcw = p & 3;

  // staging mapping (tid < 512): 64 rows x 8 threads/row, 32 fp32 each
  int sr = tid >> 3, sc8 = tid & 7;
  const float* xsrc = x + (size_t)(row0 + sr) * CDIM + sc8 * 32;
  int sbase = sr * 512;                  // LDS row byte base
  int sxor = (sr & 7) << 4;

  // A-read addressing (swizzled): row = t16*16+lr, (row&7) == (lr&7)
  int axor = (lr & 7) << 4;

  // B pointer: this wave's product; wt2 slot order is lr*4+lg
  const short* bptr = wt2 + p * 512 + (lr * 4 + lg) * 8;

  f32x4 acc[4] = {};   // [t16]

#define PLOAD(RG, PH) do {                                                   \
    _Pragma("unroll")                                                        \
    for (int q = 0; q < 8; ++q)                                              \
      RG[q] = *(const float4*)(xsrc + (PH) * 256 + q * 4);                   \
  } while (0)

#define PSTORE(RG, BUF) do {                                                 \
    char* bc_ = (char*)&xph[(BUF)][0];                                       \
    _Pragma("unroll")                                                        \
    for (int d = 0; d < 4; ++d) {                                            \
      union { unsigned u[4]; bf16x8 v; } o_;                                 \
      o_.u[0] = cvtpk(RG[d * 2].x, RG[d * 2].y);                             \
      o_.u[1] = cvtpk(RG[d * 2].z, RG[d * 2].w);                             \
      o_.u[2] = cvtpk(RG[d * 2 + 1].x, RG[d * 2 + 1].y);                     \
      o_.u[3] = cvtpk(RG[d * 2 + 1].z, RG[d * 2 + 1].w);                     \
      *(bf16x8*)(bc_ + sbase + ((sc8 * 64 + d * 16) ^ sxor)) = o_.v;         \
    }                                                                        \
  } while (0)

#define PCOMPUTE(BUF, PH) do {                                               \
    const char* bufc_ = (const char*)&xph[(BUF)][0];                         \
    _Pragma("unroll")                                                        \
    for (int kk = 0; kk < 8; ++kk) {                                         \
      int co_ = (kk * 64 + lg * 16) ^ axor;                                  \
      bf16x8 bf_ = ld8(bptr + ((PH) * 8 + kk) * 6144);                       \
      _Pragma("unroll")                                                      \
      for (int t = 0; t < 4; ++t) {                                          \
        bf16x8 af_ = *(const bf16x8*)(bufc_ + (t * 16 + lr) * 512 + co_);    \
        acc[t] = __builtin_amdgcn_mfma_f32_16x16x32_bf16(af_, bf_, acc[t], 0, 0, 0); \
      }                                                                      \
    }                                                                        \
  } while (0)

  if (tid < 512) {
    float4 rg[8];
    PLOAD(rg, 0);
    PSTORE(rg, 0);
  }
  __syncthreads();
#pragma unroll
  for (int ph = 0; ph < 4; ++ph) {
    float4 rg[8];
    if (ph < 3 && tid < 512) PLOAD(rg, ph + 1);   // issue next-phase loads early
    PCOMPUTE(ph & 1, ph);
    if (ph < 3) {
      if (tid < 512) PSTORE(rg, (ph + 1) & 1);    // write late, after compute
      __syncthreads();
    }
  }

  // ---- stores (R10-verified fragment mapping, per row-tile rt=0..3) ----
  short* qs  = ws + Q_OFF;
  short* kfr = ws + KF_OFF;
  short* vfr = ws + VF_OFF;

  if (m == 0) {
#pragma unroll
    for (int rt = 0; rt < 4; ++rt) {
      int rbase = row0 + rt * 16;
#pragma unroll
      for (int reg = 0; reg < 4; ++reg)
        qs[(rbase + lg * 4 + reg) * 64 + hcw * 16 + lr] = f2bf(acc[rt][reg]);
    }
  } else if (m == 1) {
#pragma unroll
    for (int rt = 0; rt < 4; ++rt)
#pragma unroll
      for (int reg = 0; reg < 4; ++reg)
        k_lds[hcw][rt][lg * 4 + reg][lr] = f2bf(acc[rt][reg]);   // [t16][h16]
    if (lane < 32) {
      int i0 = lane >> 1, f8 = (lane & 1) * 8;
#pragma unroll
      for (int rt = 0; rt < 4; ++rt) {
        int rbase = row0 + rt * 16;
        int b = rbase >> 12, tb = rbase & (SEQ - 1);
        int kb64 = tb >> 6, st = (tb >> 4) & 3;
        size_t kblk = ((((size_t)b * 64 + kb64) * 4 + st) * 2 + (hcw >> 1)) * 512;
        bf16x8 kv8 = *(const bf16x8*)(&k_lds[hcw][rt][i0][f8]);
        *(bf16x8*)(kfr + kblk + ((hcw & 1) * 2 + (f8 >> 3)) * 128 + i0 * 8) = kv8;
      }
    }
  } else {
#pragma unroll
    for (int rt = 0; rt < 4; ++rt)
#pragma unroll
      for (int reg = 0; reg < 4; ++reg)
        v_lds[hcw][rt][lr][lg * 4 + reg] = f2bf(acc[rt][reg]);   // [h16][t16]
    if (lane < 32) {
      int i0 = lane >> 1, f8 = (lane & 1) * 8;
#pragma unroll
      for (int rt = 0; rt < 4; ++rt) {
        int rbase = row0 + rt * 16;
        int b = rbase >> 12, tb = rbase & (SEQ - 1);
        int kb64 = tb >> 6;
        size_t vblk = ((((size_t)b * 64 + kb64) * 2 + ((tb >> 5) & 1)) * 4 + hcw) * 512;
        bf16x8 vv8 = *(const bf16x8*)(&v_lds[hcw][rt][i0][f8]);
        *(bf16x8*)(vfr + vblk + (((tb & 16) + f8) >> 3) * 128 + i0 * 8) = vv8;
      }
    }
  }
}

// ---------------- kernel 2: causal flash attention (no-max softmax) ----------
// 512 blocks x 512 thr; block g processes 16-row tiles g and 1023-g
// (heavy-first ordering -> per-block work constant). 8 waves split KV 8-way.
__global__ __launch_bounds__(512, 4) void attn_kernel(const short* __restrict__ ws,
                                                      float* __restrict__ out) {
  __shared__ float p_o[8][4][4][64];    // 32KB
  __shared__ float p_l[8][4][64];       // 8KB
  __shared__ short plds[8][16][72];     // 18KB

  int widx = threadIdx.x >> 6, lane = threadIdx.x & 63;
  int lr = lane & 15, lg = lane >> 4;
  int g = blockIdx.x;

  const short* qs  = ws + Q_OFF;
  const short* kfr = ws + KF_OFF;
  const short* vfr = ws + VF_OFF;
  short* myp = &plds[widx][0][0];

  for (int tt = 0; tt < 2; ++tt) {
    int j = tt == 0 ? g : 1023 - g;
    int t16 = 255 - (j >> 2), b = j & 3;     // heavy-first tile ordering
    int qrow0 = b * SEQ + t16 * 16;
    int nkv = (t16 >> 2) + 1;                // # of 64-wide kv blocks

    bf16x8 qf0 = ld8(qs + (qrow0 + lr) * 64 + lg * 8);
    bf16x8 qf1 = ld8(qs + (qrow0 + lr) * 64 + 32 + lg * 8);
    const short* kb_b = kfr + (size_t)b * 64 * 4096 + lane * 8;
    const short* vb_b = vfr + (size_t)b * 64 * 4096 + lane * 8;

    f32x4 o[4] = {};
    float l_run[4] = {};

    if (tt) __syncthreads();   // guard LDS reuse across tiles

    bf16x8 kf[8];
    int kvb = widx;
    if (kvb < nkv) {
      const short* kb = kb_b + (size_t)kvb * 4096;
#pragma unroll
      for (int q8 = 0; q8 < 8; ++q8) kf[q8] = ld8(kb + q8 * 512);
    }

    for (; kvb < nkv; kvb += 8) {
      int kv0 = kvb * 64;

      f32x4 s[4] = {};
#pragma unroll
      for (int st = 0; st < 4; ++st) {
        s[st] = __builtin_amdgcn_mfma_f32_16x16x32_bf16(qf0, kf[st * 2],     s[st], 0, 0, 0);
        s[st] = __builtin_amdgcn_mfma_f32_16x16x32_bf16(qf1, kf[st * 2 + 1], s[st], 0, 0, 0);
      }

      // V fragments: coalesced 1KB loads; latency hides under exp+LDS roundtrip
      bf16x8 vv[8];
      {
        const short* vb = vb_b + (size_t)kvb * 4096;
#pragma unroll
        for (int q8 = 0; q8 < 8; ++q8) vv[q8] = ld8(vb + q8 * 512);
      }
      // prefetch next K block
      int kvn = kvb + 8;
      if (kvn < nkv) {
        const short* kb = kb_b + (size_t)kvn * 4096;
#pragma unroll
        for (int q8 = 0; q8 < 8; ++q8) kf[q8] = ld8(kb + q8 * 512);
      }

      bool last = (kvb == nkv - 1);
#pragma unroll
      for (int reg = 0; reg < 4; ++reg) {
        int ig = t16 * 16 + lg * 4 + reg;
#pragma unroll
        for (int st = 0; st < 4; ++st) {
          float v = s[st][reg] * 0.125f;
          if (last && (kv0 + st * 16 + lr > ig)) v = -1e30f;
          float p = __expf(v);
          l_run[reg] += p;
          myp[(lg * 4 + reg) * 72 + st * 16 + lr] = f2bf(p);
        }
      }
      asm volatile("s_waitcnt lgkmcnt(0)" ::: "memory");
      bf16x8 pf0 = ld8(myp + lr * 72 + lg * 8);
      bf16x8 pf1 = ld8(myp + lr * 72 + 32 + lg * 8);

#pragma unroll
      for (int hc = 0; hc < 4; ++hc) {
        o[hc] = __builtin_amdgcn_mfma_f32_16x16x32_bf16(pf0, vv[hc],     o[hc], 0, 0, 0);
        o[hc] = __builtin_amdgcn_mfma_f32_16x16x32_bf16(pf1, vv[4 + hc], o[hc], 0, 0, 0);
      }
    }

    // in-lane l -> row sum
#pragma unroll
    for (int reg = 0; reg < 4; ++reg) {
      float l = l_run[reg];
      l += __shfl_xor(l, 1);
      l += __shfl_xor(l, 2);
      l += __shfl_xor(l, 4);
      l += __shfl_xor(l, 8);
      l_run[reg] = l;
    }

    // publish partials
#pragma unroll
    for (int hc = 0; hc < 4; ++hc)
#pragma unroll
      for (int reg = 0; reg < 4; ++reg)
        p_o[widx][hc][reg][lane] = o[hc][reg];
#pragma unroll
    for (int reg = 0; reg < 4; ++reg)
      p_l[widx][reg][lane] = l_run[reg];
    __syncthreads();

    // merge: waves 0-3 handle reg = widx; plain sums (no-max softmax)
    if (widx < 4) {
      int reg = widx;
      float lsum = 0.f;
#pragma unroll
      for (int w2 = 0; w2 < 8; ++w2) lsum += p_l[w2][reg][lane];
      float inv = 1.0f / lsum;
#pragma unroll
      for (int hc = 0; hc < 4; ++hc) {
        float sv = 0.f;
#pragma unroll
        for (int w2 = 0; w2 < 8; ++w2) sv += p_o[w2][hc][reg][lane];
        out[(qrow0 + lg * 4 + reg) * 64 + hc * 16 + lr] = sv * inv;
      }
    }
  }
}

extern "C" void kernel_launch(void* const* d_in, const int* in_sizes, int n_in,
                              void* d_out, int out_size, void* d_ws, size_t ws_size,
                              hipStream_t stream) {
  const float* x  = (const float*)d_in[0];
  const float* wq = (const float*)d_in[1];
  const float* wk = (const float*)d_in[2];
  const float* wv = (const float*)d_in[3];
  short* ws = (short*)d_ws;
  float* out = (float*)d_out;

  wcvt_kernel<<<dim3(768), dim3(256), 0, stream>>>(wq, wk, wv, ws + WT_OFF);
  proj_kernel<<<dim3(256), dim3(768), 0, stream>>>(x, ws + WT_OFF, ws);
  attn_kernel<<<dim3(512), dim3(512), 0, stream>>>(ws, out);
}

// Round 15
// 56.725 us; speedup vs baseline: 1.1407x; 1.0059x over previous
//
#include <hip/hip_runtime.h>

#define BATCH 4
#define SEQ   4096
#define CDIM  1024
#define HDIM  64

typedef __attribute__((ext_vector_type(8))) short bf16x8;
typedef __attribute__((ext_vector_type(4))) float f32x4;

// ws layout (in shorts):
//   wt2   [32 k0g][12 p][64 slot][8]            (bf16, frag order; slot = lr*4+lg) @ 0
//   q     [16384][64]   (bf16, row-major)       @ Q_OFF
//   kfrag [4][64 kb64][4 st][2 half][512]       @ KF_OFF
//   vfrag [4][64 kb64][2 half][4 hc][512]       @ VF_OFF
//   k/v fragment interior: [lg][lr][j] = lg*128 + lr*8 + j  (lane*8+j)
#define WT_OFF  0
#define Q_OFF   (3 * HDIM * CDIM)
#define KF_OFF  (Q_OFF + BATCH * SEQ * HDIM)
#define VF_OFF  (KF_OFF + BATCH * SEQ * HDIM)

static __device__ __forceinline__ short f2bf(float f) {
  union { float f; unsigned u; } a; a.f = f;
  unsigned r = a.u + 0x7fffu + ((a.u >> 16) & 1u);   // RNE
  return (short)(r >> 16);
}

static __device__ __forceinline__ unsigned cvtpk(float lo, float hi) {
  unsigned r;
  asm("v_cvt_pk_bf16_f32 %0, %1, %2" : "=v"(r) : "v"(lo), "v"(hi));
  return r;
}

static __device__ __forceinline__ bf16x8 ld8(const short* p) {
  return *(const bf16x8*)p;
}

// barrier that drains LDS only: global loads stay in flight (T4).
static __device__ __forceinline__ void bar_lgkm() {
  asm volatile("s_waitcnt lgkmcnt(0)\n\ts_barrier" ::: "memory");
}

// ---------------- kernel 0: W -> bf16, MFMA-fragment order ----------------
__global__ void wcvt_kernel(const float* __restrict__ wq, const float* __restrict__ wk,
                            const float* __restrict__ wv, short* __restrict__ wt2) {
  int idx = blockIdx.x * 256 + threadIdx.x;   // 0 .. 3*65536-1
  int m = idx >> 16;
  int f = idx & 65535;
  int k0g = f >> 11, hc = (f >> 9) & 3, lr = (f >> 5) & 15, lg = (f >> 3) & 3, j = f & 7;
  int c = k0g * 32 + lg * 8 + j, h = hc * 16 + lr;
  const float* w = (m == 0) ? wq : (m == 1) ? wk : wv;
  wt2[((k0g * 12 + m * 4 + hc) * 64 + lr * 4 + lg) * 8 + j] = f2bf(w[c * 64 + h]);
}

// ---------------- kernel 1: fused q/k/v projection ----------------
// block = 64 rows (4 row-tiles), 12 waves; wave p owns product p for all 4
// row-tiles (per kk: 4 ds_read + 1 B-load + 4 MFMA, B reuse x4). x staged per
// K-phase (256 cols) into XOR-swizzled LDS dbuf. Plain (compiler-tracked)
// loads issued 2 phases ahead, pinned with sched_barrier(0); lgkm-only
// barrier keeps them in flight across phase boundaries.
__global__ __launch_bounds__(768, 3) void proj_kernel(const float* __restrict__ x,
                                                      const short* __restrict__ wt2,
                                                      short* __restrict__ ws) {
  __shared__ short xph[2][64 * 256];     // 2 x 32KB, swizzled
  __shared__ short k_lds[4][4][16][16];  // [hc][rt][t16][h16]  8KB
  __shared__ short v_lds[4][4][16][16];  // [hc][rt][h16][t16]  8KB

  int tid = threadIdx.x;
  int widx = tid >> 6, lane = tid & 63;
  int lr = lane & 15, lg = lane >> 4;
  int row0 = blockIdx.x * 64;
  int p = widx;              // product id 0..11
  int m = p >> 2, hcw = p & 3;
  bool stager = (tid < 512);

  // staging mapping (tid < 512): 64 rows x 8 threads/row, 32 fp32 each
  int sr = tid >> 3, sc8 = tid & 7;
  const float* xsrc = x + (size_t)(row0 + sr) * CDIM + sc8 * 32;
  int sbase = sr * 512;                  // LDS row byte base
  int sxor = (sr & 7) << 4;

  // A-read addressing (swizzled): row = t16*16+lr, (row&7) == (lr&7)
  int axor = (lr & 7) << 4;

  // B pointer: this wave's product; wt2 slot order is lr*4+lg
  const short* bptr = wt2 + p * 512 + (lr * 4 + lg) * 8;

  f32x4 acc[4] = {};   // [t16]

#define PLOAD(RG, PH) do {                                                   \
    if (stager) {                                                            \
      _Pragma("unroll")                                                      \
      for (int q = 0; q < 8; ++q)                                            \
        RG[q] = *(const float4*)(xsrc + (PH) * 256 + q * 4);                 \
    }                                                                        \
    __builtin_amdgcn_sched_barrier(0);  /* pin issue position */             \
  } while (0)

#define PSTORE(RG, BUF) do {                                                 \
    if (stager) {                                                            \
      char* bc_ = (char*)&xph[(BUF)][0];                                     \
      _Pragma("unroll")                                                      \
      for (int d = 0; d < 4; ++d) {                                          \
        union { unsigned u[4]; bf16x8 v; } o_;                               \
        o_.u[0] = cvtpk(RG[d * 2].x, RG[d * 2].y);                           \
        o_.u[1] = cvtpk(RG[d * 2].z, RG[d * 2].w);                           \
        o_.u[2] = cvtpk(RG[d * 2 + 1].x, RG[d * 2 + 1].y);                   \
        o_.u[3] = cvtpk(RG[d * 2 + 1].z, RG[d * 2 + 1].w);                   \
        *(bf16x8*)(bc_ + sbase + ((sc8 * 64 + d * 16) ^ sxor)) = o_.v;       \
      }                                                                      \
    }                                                                        \
  } while (0)

#define PCOMPUTE(BUF, PH) do {                                               \
    const char* bufc_ = (const char*)&xph[(BUF)][0];                         \
    _Pragma("unroll")                                                        \
    for (int kk = 0; kk < 8; ++kk) {                                         \
      int co_ = (kk * 64 + lg * 16) ^ axor;                                  \
      bf16x8 bf_ = ld8(bptr + ((PH) * 8 + kk) * 6144);                       \
      _Pragma("unroll")                                                      \
      for (int t = 0; t < 4; ++t) {                                          \
        bf16x8 af_ = *(const bf16x8*)(bufc_ + (t * 16 + lr) * 512 + co_);    \
        acc[t] = __builtin_amdgcn_mfma_f32_16x16x32_bf16(af_, bf_, acc[t], 0, 0, 0); \
      }                                                                      \
    }                                                                        \
  } while (0)

  float4 rgA[8], rgB[8], rgC[8];
  // prologue: issue ph0+ph1, store ph0 (compiler emits counted vmcnt), barrier
  PLOAD(rgA, 0);
  PLOAD(rgB, 1);
  PSTORE(rgA, 0);
  bar_lgkm();                     // buf0 ready; rgB (ph1) still in flight

  // steady state: issue ph+2 | compute ph | store ph+1 | lgkm barrier
  PLOAD(rgC, 2); PCOMPUTE(0, 0); PSTORE(rgB, 1); bar_lgkm();
  PLOAD(rgA, 3); PCOMPUTE(1, 1); PSTORE(rgC, 0); bar_lgkm();
                 PCOMPUTE(0, 2); PSTORE(rgA, 1); bar_lgkm();
                 PCOMPUTE(1, 3);

  // ---- stores (R10-verified fragment mapping, per row-tile rt=0..3) ----
  short* qs  = ws + Q_OFF;
  short* kfr = ws + KF_OFF;
  short* vfr = ws + VF_OFF;

  if (m == 0) {
#pragma unroll
    for (int rt = 0; rt < 4; ++rt) {
      int rbase = row0 + rt * 16;
#pragma unroll
      for (int reg = 0; reg < 4; ++reg)
        qs[(rbase + lg * 4 + reg) * 64 + hcw * 16 + lr] = f2bf(acc[rt][reg]);
    }
  } else if (m == 1) {
#pragma unroll
    for (int rt = 0; rt < 4; ++rt)
#pragma unroll
      for (int reg = 0; reg < 4; ++reg)
        k_lds[hcw][rt][lg * 4 + reg][lr] = f2bf(acc[rt][reg]);   // [t16][h16]
    if (lane < 32) {
      int i0 = lane >> 1, f8 = (lane & 1) * 8;
#pragma unroll
      for (int rt = 0; rt < 4; ++rt) {
        int rbase = row0 + rt * 16;
        int b = rbase >> 12, tb = rbase & (SEQ - 1);
        int kb64 = tb >> 6, st = (tb >> 4) & 3;
        size_t kblk = ((((size_t)b * 64 + kb64) * 4 + st) * 2 + (hcw >> 1)) * 512;
        bf16x8 kv8 = *(const bf16x8*)(&k_lds[hcw][rt][i0][f8]);
        *(bf16x8*)(kfr + kblk + ((hcw & 1) * 2 + (f8 >> 3)) * 128 + i0 * 8) = kv8;
      }
    }
  } else {
#pragma unroll
    for (int rt = 0; rt < 4; ++rt)
#pragma unroll
      for (int reg = 0; reg < 4; ++reg)
        v_lds[hcw][rt][lr][lg * 4 + reg] = f2bf(acc[rt][reg]);   // [h16][t16]
    if (lane < 32) {
      int i0 = lane >> 1, f8 = (lane & 1) * 8;
#pragma unroll
      for (int rt = 0; rt < 4; ++rt) {
        int rbase = row0 + rt * 16;
        int b = rbase >> 12, tb = rbase & (SEQ - 1);
        int kb64 = tb >> 6;
        size_t vblk = ((((size_t)b * 64 + kb64) * 2 + ((tb >> 5) & 1)) * 4 + hcw) * 512;
        bf16x8 vv8 = *(const bf16x8*)(&v_lds[hcw][rt][i0][f8]);
        *(bf16x8*)(vfr + vblk + (((tb & 16) + f8) >> 3) * 128 + i0 * 8) = vv8;
      }
    }
  }
}

// ---------------- kernel 2: causal flash attention (no-max softmax) ----------
// 512 blocks x 512 thr; block g processes 16-row tiles g and 1023-g
// (heavy-first ordering -> per-block work constant). 8 waves split KV 8-way.
__global__ __launch_bounds__(512, 4) void attn_kernel(const short* __restrict__ ws,
                                                      float* __restrict__ out) {
  __shared__ float p_o[8][4][4][64];    // 32KB
  __shared__ float p_l[8][4][64];       // 8KB
  __shared__ short plds[8][16][72];     // 18KB

  int widx = threadIdx.x >> 6, lane = threadIdx.x & 63;
  int lr = lane & 15, lg = lane >> 4;
  int g = blockIdx.x;

  const short* qs  = ws + Q_OFF;
  const short* kfr = ws + KF_OFF;
  const short* vfr = ws + VF_OFF;
  short* myp = &plds[widx][0][0];

  for (int tt = 0; tt < 2; ++tt) {
    int j = tt == 0 ? g : 1023 - g;
    int t16 = 255 - (j >> 2), b = j & 3;     // heavy-first tile ordering
    int qrow0 = b * SEQ + t16 * 16;
    int nkv = (t16 >> 2) + 1;                // # of 64-wide kv blocks

    bf16x8 qf0 = ld8(qs + (qrow0 + lr) * 64 + lg * 8);
    bf16x8 qf1 = ld8(qs + (qrow0 + lr) * 64 + 32 + lg * 8);
    const short* kb_b = kfr + (size_t)b * 64 * 4096 + lane * 8;
    const short* vb_b = vfr + (size_t)b * 64 * 4096 + lane * 8;

    f32x4 o[4] = {};
    float l_run[4] = {};

    if (tt) __syncthreads();   // guard LDS reuse across tiles

    bf16x8 kf[8];
    int kvb = widx;
    if (kvb < nkv) {
      const short* kb = kb_b + (size_t)kvb * 4096;
#pragma unroll
      for (int q8 = 0; q8 < 8; ++q8) kf[q8] = ld8(kb + q8 * 512);
    }

    for (; kvb < nkv; kvb += 8) {
      int kv0 = kvb * 64;

      f32x4 s[4] = {};
#pragma unroll
      for (int st = 0; st < 4; ++st) {
        s[st] = __builtin_amdgcn_mfma_f32_16x16x32_bf16(qf0, kf[st * 2],     s[st], 0, 0, 0);
        s[st] = __builtin_amdgcn_mfma_f32_16x16x32_bf16(qf1, kf[st * 2 + 1], s[st], 0, 0, 0);
      }

      // V fragments: coalesced 1KB loads; latency hides under exp+LDS roundtrip
      bf16x8 vv[8];
      {
        const short* vb = vb_b + (size_t)kvb * 4096;
#pragma unroll
        for (int q8 = 0; q8 < 8; ++q8) vv[q8] = ld8(vb + q8 * 512);
      }
      // prefetch next K block
      int kvn = kvb + 8;
      if (kvn < nkv) {
        const short* kb = kb_b + (size_t)kvn * 4096;
#pragma unroll
        for (int q8 = 0; q8 < 8; ++q8) kf[q8] = ld8(kb + q8 * 512);
      }

      bool last = (kvb == nkv - 1);
#pragma unroll
      for (int reg = 0; reg < 4; ++reg) {
        int ig = t16 * 16 + lg * 4 + reg;
#pragma unroll
        for (int st = 0; st < 4; ++st) {
          float v = s[st][reg] * 0.125f;
          if (last && (kv0 + st * 16 + lr > ig)) v = -1e30f;
          float p = __expf(v);
          l_run[reg] += p;
          myp[(lg * 4 + reg) * 72 + st * 16 + lr] = f2bf(p);
        }
      }
      asm volatile("s_waitcnt lgkmcnt(0)" ::: "memory");
      bf16x8 pf0 = ld8(myp + lr * 72 + lg * 8);
      bf16x8 pf1 = ld8(myp + lr * 72 + 32 + lg * 8);

#pragma unroll
      for (int hc = 0; hc < 4; ++hc) {
        o[hc] = __builtin_amdgcn_mfma_f32_16x16x32_bf16(pf0, vv[hc],     o[hc], 0, 0, 0);
        o[hc] = __builtin_amdgcn_mfma_f32_16x16x32_bf16(pf1, vv[4 + hc], o[hc], 0, 0, 0);
      }
    }

    // in-lane l -> row sum
#pragma unroll
    for (int reg = 0; reg < 4; ++reg) {
      float l = l_run[reg];
      l += __shfl_xor(l, 1);
      l += __shfl_xor(l, 2);
      l += __shfl_xor(l, 4);
      l += __shfl_xor(l, 8);
      l_run[reg] = l;
    }

    // publish partials
#pragma unroll
    for (int hc = 0; hc < 4; ++hc)
#pragma unroll
      for (int reg = 0; reg < 4; ++reg)
        p_o[widx][hc][reg][lane] = o[hc][reg];
#pragma unroll
    for (int reg = 0; reg < 4; ++reg)
      p_l[widx][reg][lane] = l_run[reg];
    __syncthreads();

    // merge: waves 0-3 handle reg = widx; plain sums (no-max softmax)
    if (widx < 4) {
      int reg = widx;
      float lsum = 0.f;
#pragma unroll
      for (int w2 = 0; w2 < 8; ++w2) lsum += p_l[w2][reg][lane];
      float inv = 1.0f / lsum;
#pragma unroll
      for (int hc = 0; hc < 4; ++hc) {
        float sv = 0.f;
#pragma unroll
        for (int w2 = 0; w2 < 8; ++w2) sv += p_o[w2][hc][reg][lane];
        out[(qrow0 + lg * 4 + reg) * 64 + hc * 16 + lr] = sv * inv;
      }
    }
  }
}

extern "C" void kernel_launch(void* const* d_in, const int* in_sizes, int n_in,
                              void* d_out, int out_size, void* d_ws, size_t ws_size,
                              hipStream_t stream) {
  const float* x  = (const float*)d_in[0];
  const float* wq = (const float*)d_in[1];
  const float* wk = (const float*)d_in[2];
  const float* wv = (const float*)d_in[3];
  short* ws = (short*)d_ws;
  float* out = (float*)d_out;

  wcvt_kernel<<<dim3(768), dim3(256), 0, stream>>>(wq, wk, wv, ws + WT_OFF);
  proj_kernel<<<dim3(256), dim3(768), 0, stream>>>(x, ws + WT_OFF, ws);
  attn_kernel<<<dim3(512), dim3(512), 0, stream>>>(ws, out);
}